// Round 4
// baseline (120.534 us; speedup 1.0000x reference)
//
#include <hip/hip_runtime.h>
#include <cstddef>
#include <cstdint>

#define B_ 32
#define C_ 64
#define HW_ 16384
#define HW4_ 4096
#define PC_ 3
#define NCHK_ 32
#define INV_N_ (1.0f/49152.0f)

typedef __attribute__((ext_vector_type(8))) short bf16x8;
typedef __attribute__((ext_vector_type(4))) float f32x4;

// ---- output layout (float indices) ----
#define OUT_DM_   ((size_t)B_*PC_*HW_)      // predicts first: 1572864
#define OUT_IDX_  (OUT_DM_ + (size_t)B_*64)
#define OUT_LOSS_ (OUT_IDX_ + B_)
#define OUT_DIST_ (OUT_LOSS_ + B_)

// ---- workspace layout (float indices) ----
// [0..63] int idx; REDU: 32 slots; PART: 1024 slots.
// slot = 10 upper-tri 16x16 tiles (tile-major, 2560) + v(192) + r(3) -> 2755, pad 2768
#define SLOT_     2768
#define NUSED_    2755
#define REDU_OFF_ ((size_t)64)
#define PART_OFF_ (REDU_OFF_ + (size_t)B_*SLOT_)
// total ~11.7 MB (ws proven >= 17.6 MB in R2)

// split f32 -> hi/lo bf16 (RNE each), hi+lo covers ~16 mantissa bits
__device__ __forceinline__ void split2(float x, short& hs, short& ls) {
    unsigned u = __float_as_uint(x);
    unsigned hr = (u + 0x7FFFu + ((u >> 16) & 1u)) >> 16;
    float hf = __uint_as_float(hr << 16);
    float r = x - hf;                       // exact (Sterbenz)
    unsigned v = __float_as_uint(r);
    unsigned lo = (v + 0x7FFFu + ((v >> 16) & 1u)) >> 16;
    hs = (short)hr; ls = (short)lo;
}

// 4-pass split-bf16 product accumulate: C += (Ah+Al)*(Bh+Bl)
__device__ __forceinline__ f32x4 mm4(bf16x8 ah, bf16x8 al, bf16x8 bh, bf16x8 bl, f32x4 c) {
    c = __builtin_amdgcn_mfma_f32_16x16x32_bf16(ah, bh, c, 0, 0, 0);
    c = __builtin_amdgcn_mfma_f32_16x16x32_bf16(ah, bl, c, 0, 0, 0);
    c = __builtin_amdgcn_mfma_f32_16x16x32_bf16(al, bh, c, 0, 0, 0);
    c = __builtin_amdgcn_mfma_f32_16x16x32_bf16(al, bl, c, 0, 0, 0);
    return c;
}

__device__ __forceinline__ void acc_dump(float* d, const f32x4* a) {
#pragma unroll
    for (int tt = 0; tt < 15; ++tt)
#pragma unroll
        for (int q = 0; q < 4; ++q) d[tt * 4 + q] = a[tt][q];
}
__device__ __forceinline__ void acc_add(f32x4* a, const float* d) {
#pragma unroll
    for (int tt = 0; tt < 15; ++tt)
#pragma unroll
        for (int q = 0; q < 4; ++q) a[tt][q] += d[tt * 4 + q];
}

// =====================================================================
// K1: per (b, chunk of 512 px): M = sum f f^T (upper tiles), v = sum f*r,
// rsq = sum r^2 via split-bf16 MFMA. 4 waves x 128 px x 4 steps.
// Register-pipelined: convert step s, then issue s+1 loads under the MFMAs.
// =====================================================================
__global__ __launch_bounds__(256, 3)
void k1_stats(const float* __restrict__ feat, const float* __restrict__ target,
              const float* __restrict__ pred, float* __restrict__ ws) {
    const int b = blockIdx.x >> 5, chunk = blockIdx.x & 31;
    const int t = threadIdx.x, wv = t >> 6, lane = t & 63;
    const int lr = lane & 15, lg = lane >> 4;

    // tiles: 0-9 = M upper (gi<=gj), 10-13 = v (r x Fg), 14 = r x r
    f32x4 acc[15];
#pragma unroll
    for (int i = 0; i < 15; ++i) acc[i] = (f32x4){0.f, 0.f, 0.f, 0.f};

    const int px0 = chunk * 512 + wv * 128 + lg * 8;
    const float* fp = feat   + (size_t)(b * 64 + lr) * HW_ + px0;
    const float* pp = pred   + (size_t)(b * 3 + lr) * HW_ + px0;   // valid lr<3
    const float* tp = target + (size_t)(b * 3 + lr) * HW_ + px0;

    float4 fb0[4], fb1[4];
    float4 pb0 = {0,0,0,0}, pb1 = {0,0,0,0}, tb0 = {0,0,0,0}, tb1 = {0,0,0,0};

#define LOADS_(s) {                                                            \
    _Pragma("unroll")                                                          \
    for (int g = 0; g < 4; ++g) {                                              \
        const float4* q_ = (const float4*)(fp + (size_t)g * (16 * HW_) + (s) * 32); \
        fb0[g] = q_[0]; fb1[g] = q_[1];                                        \
    }                                                                          \
    if (lr < 3) {                                                              \
        const float4* qp_ = (const float4*)(pp + (s) * 32);                    \
        const float4* qt_ = (const float4*)(tp + (s) * 32);                    \
        pb0 = qp_[0]; pb1 = qp_[1]; tb0 = qt_[0]; tb1 = qt_[1];                \
    } }

    LOADS_(0);

#pragma unroll
    for (int s = 0; s < 4; ++s) {
        // convert staged regs (waits only on this step's loads)
        bf16x8 Fh[4], Fl[4], Rh, Rl;
#pragma unroll
        for (int g = 0; g < 4; ++g) {
            const float fx[8] = {fb0[g].x, fb0[g].y, fb0[g].z, fb0[g].w,
                                 fb1[g].x, fb1[g].y, fb1[g].z, fb1[g].w};
#pragma unroll
            for (int i = 0; i < 8; ++i) {
                short h, l; split2(fx[i], h, l);
                Fh[g][i] = h; Fl[g][i] = l;
            }
        }
        {
            const float rx[8] = {pb0.x-tb0.x, pb0.y-tb0.y, pb0.z-tb0.z, pb0.w-tb0.w,
                                 pb1.x-tb1.x, pb1.y-tb1.y, pb1.z-tb1.z, pb1.w-tb1.w};
#pragma unroll
            for (int i = 0; i < 8; ++i) {
                short h, l; split2(rx[i], h, l);
                Rh[i] = h; Rl[i] = l;
            }
        }
        // staging regs now dead -> issue next step's loads; they fly under MFMAs
        if (s < 3) { LOADS_(s + 1); }

        acc[0]  = mm4(Fh[0], Fl[0], Fh[0], Fl[0], acc[0]);
        acc[1]  = mm4(Fh[0], Fl[0], Fh[1], Fl[1], acc[1]);
        acc[2]  = mm4(Fh[0], Fl[0], Fh[2], Fl[2], acc[2]);
        acc[3]  = mm4(Fh[0], Fl[0], Fh[3], Fl[3], acc[3]);
        acc[4]  = mm4(Fh[1], Fl[1], Fh[1], Fl[1], acc[4]);
        acc[5]  = mm4(Fh[1], Fl[1], Fh[2], Fl[2], acc[5]);
        acc[6]  = mm4(Fh[1], Fl[1], Fh[3], Fl[3], acc[6]);
        acc[7]  = mm4(Fh[2], Fl[2], Fh[2], Fl[2], acc[7]);
        acc[8]  = mm4(Fh[2], Fl[2], Fh[3], Fl[3], acc[8]);
        acc[9]  = mm4(Fh[3], Fl[3], Fh[3], Fl[3], acc[9]);
        acc[10] = mm4(Rh, Rl, Fh[0], Fl[0], acc[10]);
        acc[11] = mm4(Rh, Rl, Fh[1], Fl[1], acc[11]);
        acc[12] = mm4(Rh, Rl, Fh[2], Fl[2], acc[12]);
        acc[13] = mm4(Rh, Rl, Fh[3], Fl[3], acc[13]);
        acc[14] = mm4(Rh, Rl, Rh, Rl, acc[14]);
    }
#undef LOADS_

    // ---- deterministic 4-wave tree reduce (stride 69 -> conflict-free) ----
    __shared__ __align__(16) float buf[2][64][69];
    float* b0p = &buf[0][lane][0];
    float* b1p = &buf[1][lane][0];
    if (wv == 2) acc_dump(b0p, acc);
    if (wv == 3) acc_dump(b1p, acc);
    __syncthreads();
    if (wv == 0) acc_add(acc, b0p);
    if (wv == 1) acc_add(acc, b1p);
    __syncthreads();
    if (wv == 1) acc_dump(b0p, acc);
    __syncthreads();

    if (wv == 0) {
        acc_add(acc, b0p);
        float* P = ws + PART_OFF_ + (size_t)blockIdx.x * SLOT_;
        // tile-major, coalesced 256B stores; element e=q*64+lane <->
        // (row16 = ((e>>4)&3)*4 + (e>>6), col16 = e&15)
#pragma unroll
        for (int tt = 0; tt < 10; ++tt)
#pragma unroll
            for (int q = 0; q < 4; ++q)
                P[tt * 256 + q * 64 + lane] = acc[tt][q];
        if (lg == 0) {   // v rows 0..2 live in regs q=0..2 of lanes 0..15
#pragma unroll
            for (int gj = 0; gj < 4; ++gj) {
                P[2560 + 0 * 64 + gj * 16 + lr] = acc[10 + gj][0];
                P[2560 + 1 * 64 + gj * 16 + lr] = acc[10 + gj][1];
                P[2560 + 2 * 64 + gj * 16 + lr] = acc[10 + gj][2];
            }
        }
        if (lane == 0) P[2752] = acc[14][0];
        if (lane == 1) P[2753] = acc[14][1];
        if (lane == 2) P[2754] = acc[14][2];
    }
}

// =====================================================================
// K2a: grid-wide reduce of 32 partial slots per b (352 blocks)
// =====================================================================
__global__ __launch_bounds__(256)
void k2a_reduce(float* __restrict__ ws) {
    const int b = blockIdx.x / 11, blk = blockIdx.x % 11;
    const int pos = blk * 256 + threadIdx.x;
    if (pos >= NUSED_) return;
    const float* P = ws + PART_OFF_ + (size_t)b * NCHK_ * SLOT_ + pos;
    float s = 0.f;
#pragma unroll
    for (int c = 0; c < NCHK_; ++c) s += P[(size_t)c * SLOT_];
    ws[REDU_OFF_ + (size_t)b * SLOT_ + pos] = s;
}

// =====================================================================
// K2b: rebuild M (mirror), dist_k = (w^T M w + 2 w.v + rsq)/N; argmin.
// =====================================================================
__global__ __launch_bounds__(256)
void k2b_dist(const float* __restrict__ weight, float* __restrict__ ws,
              float* __restrict__ dout) {
    const int b = blockIdx.x, t = threadIdx.x;
    __shared__ __align__(16) float Ml[64][64];
    __shared__ __align__(16) float vl[192];
    __shared__ float red[3][64];
    __shared__ float rl;

    const float* R = ws + REDU_OFF_ + (size_t)b * SLOT_;
    const int TI[10] = {0,0,0,0,1,1,1,2,2,3};
    const int TJ[10] = {0,1,2,3,1,2,3,2,3,3};
    {
        const int q = t >> 6, lg2 = (t >> 4) & 3, lr2 = t & 15;
        const int r16 = lg2 * 4 + q, c16 = lr2;
#pragma unroll
        for (int r = 0; r < 10; ++r) {
            const int gi = TI[r], gj = TJ[r];
            const float val = R[r * 256 + t];
            Ml[gi * 16 + r16][gj * 16 + c16] = val;
            if (gi != gj) Ml[gj * 16 + c16][gi * 16 + r16] = val;
        }
    }
    if (t < 192) vl[t] = R[2560 + t];
    if (t == 0) rl = R[2752] + R[2753] + R[2754];
    __syncthreads();

    if (t < 192) {
        const int k = t & 63, pc = t >> 6;
        const float4* wr = (const float4*)(weight + (size_t)(3 * k + pc) * 64);
        float4 w[16];
#pragma unroll
        for (int j = 0; j < 16; ++j) w[j] = wr[j];
        float s = 0.f;
#pragma unroll 2
        for (int i4 = 0; i4 < 16; ++i4) {
            const float wi[4] = {w[i4].x, w[i4].y, w[i4].z, w[i4].w};
#pragma unroll
            for (int ii = 0; ii < 4; ++ii) {
                const int i = i4 * 4 + ii;
                const float4* Mr = (const float4*)&Ml[i][0];
                float4 ya = make_float4(0.f, 0.f, 0.f, 0.f);
#pragma unroll
                for (int j = 0; j < 16; ++j) {
                    ya.x += Mr[j].x * w[j].x; ya.y += Mr[j].y * w[j].y;
                    ya.z += Mr[j].z * w[j].z; ya.w += Mr[j].w * w[j].w;
                }
                s += wi[ii] * (ya.x + ya.y + ya.z + ya.w);
            }
        }
        const float4* vl4 = (const float4*)&vl[pc * 64];
        float4 sv = make_float4(0.f, 0.f, 0.f, 0.f);
#pragma unroll
        for (int j = 0; j < 16; ++j) {
            sv.x += vl4[j].x * w[j].x; sv.y += vl4[j].y * w[j].y;
            sv.z += vl4[j].z * w[j].z; sv.w += vl4[j].w * w[j].w;
        }
        red[pc][k] = s + 2.f * (sv.x + sv.y + sv.z + sv.w);
    }
    __syncthreads();
    if (t < 64) {
        float d = (red[0][t] + red[1][t] + red[2][t] + rl) * INV_N_;
        dout[OUT_DM_ + (size_t)b * 64 + t] = d;
        int idx = t;
#pragma unroll
        for (int off = 32; off >= 1; off >>= 1) {
            const float od = __shfl_xor(d, off);
            const int   oi = __shfl_xor(idx, off);
            if (od < d || (od == d && oi < idx)) { d = od; idx = oi; }
        }
        if (t == 0) {
            ((int*)ws)[b] = idx;
            dout[OUT_IDX_  + b] = (float)idx;
            dout[OUT_LOSS_ + b] = d;   // loss == distances mathematically
            dout[OUT_DIST_ + b] = d;
        }
    }
}

// =====================================================================
// K4: winning candidate only. 2048 blocks (32 waves/CU); 4 waves split
// the channel dim (16 each) and combine via LDS.
// =====================================================================
__global__ __launch_bounds__(256)
void k4_pred(const float* __restrict__ feat, const float* __restrict__ predl,
             const float* __restrict__ weight, const float* __restrict__ ws,
             float* __restrict__ dout) {
    const int b = blockIdx.x >> 6, sb = blockIdx.x & 63;
    const int t = threadIdx.x, lane = t & 63, wv = t >> 6;
    __shared__ float wl[PC_][64];
    __shared__ __align__(16) float4 red[3][PC_][64];
    const int kbest = ((const int*)ws)[b];
    if (t < 192) wl[t >> 6][t & 63] = weight[(size_t)(kbest * 3 + (t >> 6)) * 64 + (t & 63)];
    __syncthreads();
    const int hw4 = sb * 64 + lane;
    const float4* f4 = (const float4*)feat;
    const size_t base4 = (size_t)b * C_ * HW4_ + hw4;
    float4 a0 = {0,0,0,0}, a1 = {0,0,0,0}, a2 = {0,0,0,0};
#pragma unroll
    for (int i = 0; i < 16; ++i) {
        const int c = wv * 16 + i;
        const float4 f = f4[base4 + (size_t)c * HW4_];
        const float w0 = wl[0][c], w1 = wl[1][c], w2 = wl[2][c];
        a0.x += f.x*w0; a0.y += f.y*w0; a0.z += f.z*w0; a0.w += f.w*w0;
        a1.x += f.x*w1; a1.y += f.y*w1; a1.z += f.z*w1; a1.w += f.w*w1;
        a2.x += f.x*w2; a2.y += f.y*w2; a2.z += f.z*w2; a2.w += f.w*w2;
    }
    const float4* p4 = (const float4*)predl;
    const size_t ob = (size_t)b * PC_ * HW4_ + hw4;
    float4 pl0, pl1, pl2;
    if (wv == 0) { pl0 = p4[ob]; pl1 = p4[ob + 4096]; pl2 = p4[ob + 8192]; }
    else { red[wv-1][0][lane] = a0; red[wv-1][1][lane] = a1; red[wv-1][2][lane] = a2; }
    __syncthreads();
    if (wv == 0) {
#pragma unroll
        for (int w = 0; w < 3; ++w) {
            const float4 x0 = red[w][0][lane], x1 = red[w][1][lane], x2 = red[w][2][lane];
            a0.x += x0.x; a0.y += x0.y; a0.z += x0.z; a0.w += x0.w;
            a1.x += x1.x; a1.y += x1.y; a1.z += x1.z; a1.w += x1.w;
            a2.x += x2.x; a2.y += x2.y; a2.z += x2.z; a2.w += x2.w;
        }
        a0.x += pl0.x; a0.y += pl0.y; a0.z += pl0.z; a0.w += pl0.w;
        a1.x += pl1.x; a1.y += pl1.y; a1.z += pl1.z; a1.w += pl1.w;
        a2.x += pl2.x; a2.y += pl2.y; a2.z += pl2.z; a2.w += pl2.w;
        float4* o4 = (float4*)dout;
        o4[ob]        = a0;
        o4[ob + 4096] = a1;
        o4[ob + 8192] = a2;
    }
}

extern "C" void kernel_launch(void* const* d_in, const int* in_sizes, int n_in,
                              void* d_out, int out_size, void* d_ws, size_t ws_size,
                              hipStream_t stream) {
    const float* feat   = (const float*)d_in[0];
    const float* target = (const float*)d_in[1];
    const float* predl  = (const float*)d_in[2];
    const float* weight = (const float*)d_in[3];
    float* out = (float*)d_out;
    float* wsf = (float*)d_ws;
    (void)ws_size;

    hipLaunchKernelGGL(k1_stats, dim3(B_ * NCHK_), dim3(256), 0, stream,
                       feat, target, predl, wsf);
    hipLaunchKernelGGL(k2a_reduce, dim3(B_ * 11), dim3(256), 0, stream, wsf);
    hipLaunchKernelGGL(k2b_dist, dim3(B_), dim3(256), 0, stream,
                       weight, wsf, out);
    hipLaunchKernelGGL(k4_pred, dim3(B_ * 64), dim3(256), 0, stream,
                       feat, predl, weight, wsf, out);
}

// Round 6
// 101.500 us; speedup vs baseline: 1.1875x; 1.1875x over previous
//
#include <hip/hip_runtime.h>
#include <cstddef>
#include <cstdint>

#define B_ 32
#define C_ 64
#define HW_ 16384
#define HW4_ 4096
#define PC_ 3
#define NCHK_ 32
#define INV_N_ (1.0f/49152.0f)

typedef __attribute__((ext_vector_type(8))) short bf16x8;
typedef __attribute__((ext_vector_type(4))) short s16x4;
typedef __attribute__((ext_vector_type(4))) float f32x4;

// ---- output layout (float indices) ----
#define OUT_DM_   ((size_t)B_*PC_*HW_)      // predicts first: 1572864
#define OUT_IDX_  (OUT_DM_ + (size_t)B_*64)
#define OUT_LOSS_ (OUT_IDX_ + B_)
#define OUT_DIST_ (OUT_LOSS_ + B_)

// ---- workspace layout (float indices) ----
// [0..63] int idx; REDU: 32 slots; PART: 1024 slots.
// slot = 10 upper-tri 16x16 tiles (tile-major, 2560) + v(192) + r(3) -> 2755, pad 2768
#define SLOT_     2768
#define NUSED_    2755
#define REDU_OFF_ ((size_t)64)
#define PART_OFF_ (REDU_OFF_ + (size_t)B_*SLOT_)

// split f32 -> hi/lo bf16 (RNE each), hi+lo covers ~16 mantissa bits
__device__ __forceinline__ void split2(float x, short& hs, short& ls) {
    unsigned u = __float_as_uint(x);
    unsigned hr = (u + 0x7FFFu + ((u >> 16) & 1u)) >> 16;
    float hf = __uint_as_float(hr << 16);
    float r = x - hf;                       // exact
    unsigned v = __float_as_uint(r);
    unsigned lo = (v + 0x7FFFu + ((v >> 16) & 1u)) >> 16;
    hs = (short)hr; ls = (short)lo;
}

// 4-pass split-bf16 product accumulate: C += (Ah+Al)*(Bh+Bl)
__device__ __forceinline__ f32x4 mm4(bf16x8 ah, bf16x8 al, bf16x8 bh, bf16x8 bl, f32x4 c) {
    c = __builtin_amdgcn_mfma_f32_16x16x32_bf16(ah, bh, c, 0, 0, 0);
    c = __builtin_amdgcn_mfma_f32_16x16x32_bf16(ah, bl, c, 0, 0, 0);
    c = __builtin_amdgcn_mfma_f32_16x16x32_bf16(al, bh, c, 0, 0, 0);
    c = __builtin_amdgcn_mfma_f32_16x16x32_bf16(al, bl, c, 0, 0, 0);
    return c;
}

// fragment read from XOR-swizzled hi/lo planes (row stride 128B)
__device__ __forceinline__ void fragF(const short (*pH)[64], const short (*pL)[64],
                                      int ch, int koff, bf16x8& h, bf16x8& l) {
    const int off = koff ^ ((ch & 7) << 3);
    h = *(const bf16x8*)&pH[ch][off];
    l = *(const bf16x8*)&pL[ch][off];
}

// =====================================================================
// K1: per (b, chunk of 512 px): M = sum f f^T (10 upper 16x16 tiles),
// v[pc] = sum f*r, rsq = sum r^2 via split-bf16 MFMA.
// Coalesced global->reg; split to bf16 hi/lo ONCE at staging; XOR-swizzled
// LDS planes (conflict-free b128); double-buffered, loads 2 tiles ahead.
// The 15 output tiles are partitioned across the 4 waves (no redundancy,
// no cross-wave reduce): w0:{M00,M01,M02,M03} w1:{M11,M12,M13,M22}
// w2:{M23,M33,v0,v1} w3:{v2,v3,rr}.
// =====================================================================
__global__ __launch_bounds__(256, 4)
void k1_stats(const float* __restrict__ feat, const float* __restrict__ target,
              const float* __restrict__ pred, float* __restrict__ ws) {
    const int b = blockIdx.x >> 5, chunk = blockIdx.x & 31;
    const int t = threadIdx.x, wv = t >> 6, lane = t & 63;
    const int lr = lane & 15, lg = lane >> 4;
    const int row16 = t >> 4, px4 = t & 15;

    __shared__ __align__(16) short fH[2][64][64];   // 16 KB
    __shared__ __align__(16) short fL[2][64][64];   // 16 KB
    __shared__ __align__(16) short rH[2][3][64];
    __shared__ __align__(16) short rL[2][3][64];

    f32x4 acc[4];
#pragma unroll
    for (int i = 0; i < 4; ++i) acc[i] = (f32x4){0.f, 0.f, 0.f, 0.f};

    const float4* feat4 = (const float4*)feat;
    const float4* pred4 = (const float4*)pred;
    const float4* targ4 = (const float4*)target;
    const size_t cbase4 = (size_t)chunk * 128;      // 512 px = 128 float4
    const size_t fbase  = (size_t)b * 64 * HW4_ + (size_t)row16 * HW4_ + cbase4 + px4;
    const size_t rbase  = ((size_t)b * 3 + row16) * HW4_ + cbase4 + px4;  // valid t<48

    float4 sf[4], sp, st;

#define LOAD_TILE_(tl) {                                                     \
    _Pragma("unroll")                                                        \
    for (int i = 0; i < 4; ++i)                                              \
        sf[i] = feat4[fbase + (size_t)(16 * i) * HW4_ + (tl) * 16];          \
    if (t < 48) { sp = pred4[rbase + (tl) * 16];                             \
                  st = targ4[rbase + (tl) * 16]; } }

#define WRITE_TILE_(nb) {                                                    \
    _Pragma("unroll")                                                        \
    for (int i = 0; i < 4; ++i) {                                            \
        const int ch = row16 + 16 * i;                                       \
        const int so = (px4 * 4) ^ ((ch & 7) << 3);                          \
        const float fx[4] = {sf[i].x, sf[i].y, sf[i].z, sf[i].w};            \
        s16x4 hv, lv;                                                        \
        _Pragma("unroll")                                                    \
        for (int j = 0; j < 4; ++j) {                                        \
            short h_, l_; split2(fx[j], h_, l_); hv[j] = h_; lv[j] = l_; }   \
        *(s16x4*)&fH[nb][ch][so] = hv;                                       \
        *(s16x4*)&fL[nb][ch][so] = lv;                                       \
    }                                                                        \
    if (t < 48) {                                                            \
        const int so = (px4 * 4) ^ (row16 << 3);                             \
        const float rx[4] = {sp.x - st.x, sp.y - st.y, sp.z - st.z, sp.w - st.w}; \
        s16x4 hv, lv;                                                        \
        _Pragma("unroll")                                                    \
        for (int j = 0; j < 4; ++j) {                                        \
            short h_, l_; split2(rx[j], h_, l_); hv[j] = h_; lv[j] = l_; }   \
        *(s16x4*)&rH[nb][row16][so] = hv;                                    \
        *(s16x4*)&rL[nb][row16][so] = lv;                                    \
    } }

    LOAD_TILE_(0);
    WRITE_TILE_(0);
    LOAD_TILE_(1);                 // in flight during first compute
    __syncthreads();

    for (int tile = 0; tile < 8; ++tile) {
        const int cur = tile & 1;
#pragma unroll
        for (int ks = 0; ks < 2; ++ks) {
            const int ko = ks * 32 + lg * 8;
            if (wv == 0) {
                bf16x8 a0h,a0l,a1h,a1l,a2h,a2l,a3h,a3l;
                fragF(fH[cur], fL[cur], lr,      ko, a0h, a0l);
                fragF(fH[cur], fL[cur], 16 + lr, ko, a1h, a1l);
                fragF(fH[cur], fL[cur], 32 + lr, ko, a2h, a2l);
                fragF(fH[cur], fL[cur], 48 + lr, ko, a3h, a3l);
                acc[0] = mm4(a0h, a0l, a0h, a0l, acc[0]);   // M(0,0)
                acc[1] = mm4(a0h, a0l, a1h, a1l, acc[1]);   // M(0,1)
                acc[2] = mm4(a0h, a0l, a2h, a2l, acc[2]);   // M(0,2)
                acc[3] = mm4(a0h, a0l, a3h, a3l, acc[3]);   // M(0,3)
            } else if (wv == 1) {
                bf16x8 a1h,a1l,a2h,a2l,a3h,a3l;
                fragF(fH[cur], fL[cur], 16 + lr, ko, a1h, a1l);
                fragF(fH[cur], fL[cur], 32 + lr, ko, a2h, a2l);
                fragF(fH[cur], fL[cur], 48 + lr, ko, a3h, a3l);
                acc[0] = mm4(a1h, a1l, a1h, a1l, acc[0]);   // M(1,1)
                acc[1] = mm4(a1h, a1l, a2h, a2l, acc[1]);   // M(1,2)
                acc[2] = mm4(a1h, a1l, a3h, a3l, acc[2]);   // M(1,3)
                acc[3] = mm4(a2h, a2l, a2h, a2l, acc[3]);   // M(2,2)
            } else if (wv == 2) {
                bf16x8 a0h,a0l,a1h,a1l,a2h,a2l,a3h,a3l;
                bf16x8 rh = {0,0,0,0,0,0,0,0}, rl = {0,0,0,0,0,0,0,0};
                fragF(fH[cur], fL[cur], lr,      ko, a0h, a0l);
                fragF(fH[cur], fL[cur], 16 + lr, ko, a1h, a1l);
                fragF(fH[cur], fL[cur], 32 + lr, ko, a2h, a2l);
                fragF(fH[cur], fL[cur], 48 + lr, ko, a3h, a3l);
                if (lr < 3) {
                    const int off = ko ^ (lr << 3);
                    rh = *(const bf16x8*)&rH[cur][lr][off];
                    rl = *(const bf16x8*)&rL[cur][lr][off];
                }
                acc[0] = mm4(a2h, a2l, a3h, a3l, acc[0]);   // M(2,3)
                acc[1] = mm4(a3h, a3l, a3h, a3l, acc[1]);   // M(3,3)
                acc[2] = mm4(rh, rl, a0h, a0l, acc[2]);     // v0
                acc[3] = mm4(rh, rl, a1h, a1l, acc[3]);     // v1
            } else {
                bf16x8 a2h,a2l,a3h,a3l;
                bf16x8 rh = {0,0,0,0,0,0,0,0}, rl = {0,0,0,0,0,0,0,0};
                fragF(fH[cur], fL[cur], 32 + lr, ko, a2h, a2l);
                fragF(fH[cur], fL[cur], 48 + lr, ko, a3h, a3l);
                if (lr < 3) {
                    const int off = ko ^ (lr << 3);
                    rh = *(const bf16x8*)&rH[cur][lr][off];
                    rl = *(const bf16x8*)&rL[cur][lr][off];
                }
                acc[0] = mm4(rh, rl, a2h, a2l, acc[0]);     // v2
                acc[1] = mm4(rh, rl, a3h, a3l, acc[1]);     // v3
                acc[2] = mm4(rh, rl, rh, rl, acc[2]);       // r x r
            }
        }
        if (tile < 7) {
            WRITE_TILE_(cur ^ 1);          // waits vmcnt for tile+1's loads
            if (tile < 6) { LOAD_TILE_(tile + 2); }
            __syncthreads();
        }
    }
#undef LOAD_TILE_
#undef WRITE_TILE_

    // ---- epilogue: each wave owns its tiles; direct coalesced stores ----
    // tile-major layout; element e=q*64+lane <-> (row16 = (lane>>4)*4+q, col16 = lane&15)
    float* P = ws + PART_OFF_ + (size_t)blockIdx.x * SLOT_;
    if (wv == 0) {
#pragma unroll
        for (int tt = 0; tt < 4; ++tt)
#pragma unroll
            for (int q = 0; q < 4; ++q)
                P[tt * 256 + q * 64 + lane] = acc[tt][q];
    } else if (wv == 1) {
#pragma unroll
        for (int tt = 0; tt < 4; ++tt)
#pragma unroll
            for (int q = 0; q < 4; ++q)
                P[(4 + tt) * 256 + q * 64 + lane] = acc[tt][q];
    } else if (wv == 2) {
#pragma unroll
        for (int q = 0; q < 4; ++q) {
            P[8 * 256 + q * 64 + lane] = acc[0][q];
            P[9 * 256 + q * 64 + lane] = acc[1][q];
        }
        if (lg == 0) {   // v[pc][ch]: rows pc=0..2 live in regs q=0..2, lanes 0..15
            P[2560 + 0 * 64 +  0 + lr] = acc[2][0];
            P[2560 + 1 * 64 +  0 + lr] = acc[2][1];
            P[2560 + 2 * 64 +  0 + lr] = acc[2][2];
            P[2560 + 0 * 64 + 16 + lr] = acc[3][0];
            P[2560 + 1 * 64 + 16 + lr] = acc[3][1];
            P[2560 + 2 * 64 + 16 + lr] = acc[3][2];
        }
    } else {
        if (lg == 0) {
            P[2560 + 0 * 64 + 32 + lr] = acc[0][0];
            P[2560 + 1 * 64 + 32 + lr] = acc[0][1];
            P[2560 + 2 * 64 + 32 + lr] = acc[0][2];
            P[2560 + 0 * 64 + 48 + lr] = acc[1][0];
            P[2560 + 1 * 64 + 48 + lr] = acc[1][1];
            P[2560 + 2 * 64 + 48 + lr] = acc[1][2];
        }
        if (lane == 0) P[2752] = acc[2][0];
        if (lane == 1) P[2753] = acc[2][1];
        if (lane == 2) P[2754] = acc[2][2];
    }
}

// =====================================================================
// K2a: grid-wide reduce of 32 partial slots per b (352 blocks)
// =====================================================================
__global__ __launch_bounds__(256)
void k2a_reduce(float* __restrict__ ws) {
    const int b = blockIdx.x / 11, blk = blockIdx.x % 11;
    const int pos = blk * 256 + threadIdx.x;
    if (pos >= NUSED_) return;
    const float* P = ws + PART_OFF_ + (size_t)b * NCHK_ * SLOT_ + pos;
    float s = 0.f;
#pragma unroll
    for (int c = 0; c < NCHK_; ++c) s += P[(size_t)c * SLOT_];
    ws[REDU_OFF_ + (size_t)b * SLOT_ + pos] = s;
}

// =====================================================================
// K2b: rebuild M (mirror), dist_k = (w^T M w + 2 w.v + rsq)/N; argmin.
// =====================================================================
__global__ __launch_bounds__(256)
void k2b_dist(const float* __restrict__ weight, float* __restrict__ ws,
              float* __restrict__ dout) {
    const int b = blockIdx.x, t = threadIdx.x;
    __shared__ __align__(16) float Ml[64][64];
    __shared__ __align__(16) float vl[192];
    __shared__ float red[3][64];
    __shared__ float rl;

    const float* R = ws + REDU_OFF_ + (size_t)b * SLOT_;
    const int TI[10] = {0,0,0,0,1,1,1,2,2,3};
    const int TJ[10] = {0,1,2,3,1,2,3,2,3,3};
    {
        const int q = t >> 6, lg2 = (t >> 4) & 3, lr2 = t & 15;
        const int r16 = lg2 * 4 + q, c16 = lr2;
#pragma unroll
        for (int r = 0; r < 10; ++r) {
            const int gi = TI[r], gj = TJ[r];
            const float val = R[r * 256 + t];
            Ml[gi * 16 + r16][gj * 16 + c16] = val;
            if (gi != gj) Ml[gj * 16 + c16][gi * 16 + r16] = val;
        }
    }
    if (t < 192) vl[t] = R[2560 + t];
    if (t == 0) rl = R[2752] + R[2753] + R[2754];
    __syncthreads();

    if (t < 192) {
        const int k = t & 63, pc = t >> 6;
        const float4* wr = (const float4*)(weight + (size_t)(3 * k + pc) * 64);
        float4 w[16];
#pragma unroll
        for (int j = 0; j < 16; ++j) w[j] = wr[j];
        float s = 0.f;
#pragma unroll 2
        for (int i4 = 0; i4 < 16; ++i4) {
            const float wi[4] = {w[i4].x, w[i4].y, w[i4].z, w[i4].w};
#pragma unroll
            for (int ii = 0; ii < 4; ++ii) {
                const int i = i4 * 4 + ii;
                const float4* Mr = (const float4*)&Ml[i][0];
                float4 ya = make_float4(0.f, 0.f, 0.f, 0.f);
#pragma unroll
                for (int j = 0; j < 16; ++j) {
                    ya.x += Mr[j].x * w[j].x; ya.y += Mr[j].y * w[j].y;
                    ya.z += Mr[j].z * w[j].z; ya.w += Mr[j].w * w[j].w;
                }
                s += wi[ii] * (ya.x + ya.y + ya.z + ya.w);
            }
        }
        const float4* vl4 = (const float4*)&vl[pc * 64];
        float4 sv = make_float4(0.f, 0.f, 0.f, 0.f);
#pragma unroll
        for (int j = 0; j < 16; ++j) {
            sv.x += vl4[j].x * w[j].x; sv.y += vl4[j].y * w[j].y;
            sv.z += vl4[j].z * w[j].z; sv.w += vl4[j].w * w[j].w;
        }
        red[pc][k] = s + 2.f * (sv.x + sv.y + sv.z + sv.w);
    }
    __syncthreads();
    if (t < 64) {
        float d = (red[0][t] + red[1][t] + red[2][t] + rl) * INV_N_;
        dout[OUT_DM_ + (size_t)b * 64 + t] = d;
        int idx = t;
#pragma unroll
        for (int off = 32; off >= 1; off >>= 1) {
            const float od = __shfl_xor(d, off);
            const int   oi = __shfl_xor(idx, off);
            if (od < d || (od == d && oi < idx)) { d = od; idx = oi; }
        }
        if (t == 0) {
            ((int*)ws)[b] = idx;
            dout[OUT_IDX_  + b] = (float)idx;
            dout[OUT_LOSS_ + b] = d;   // loss == distances mathematically
            dout[OUT_DIST_ + b] = d;
        }
    }
}

// =====================================================================
// K4: winning candidate only. 2048 blocks; 4 waves split the channel dim
// (16 each) and combine via LDS.
// =====================================================================
__global__ __launch_bounds__(256)
void k4_pred(const float* __restrict__ feat, const float* __restrict__ predl,
             const float* __restrict__ weight, const float* __restrict__ ws,
             float* __restrict__ dout) {
    const int b = blockIdx.x >> 6, sb = blockIdx.x & 63;
    const int t = threadIdx.x, lane = t & 63, wv = t >> 6;
    __shared__ float wl[PC_][64];
    __shared__ __align__(16) float4 red[3][PC_][64];
    const int kbest = ((const int*)ws)[b];
    if (t < 192) wl[t >> 6][t & 63] = weight[(size_t)(kbest * 3 + (t >> 6)) * 64 + (t & 63)];
    __syncthreads();
    const int hw4 = sb * 64 + lane;
    const float4* f4 = (const float4*)feat;
    const size_t base4 = (size_t)b * C_ * HW4_ + hw4;
    float4 a0 = {0,0,0,0}, a1 = {0,0,0,0}, a2 = {0,0,0,0};
#pragma unroll
    for (int i = 0; i < 16; ++i) {
        const int c = wv * 16 + i;
        const float4 f = f4[base4 + (size_t)c * HW4_];
        const float w0 = wl[0][c], w1 = wl[1][c], w2 = wl[2][c];
        a0.x += f.x*w0; a0.y += f.y*w0; a0.z += f.z*w0; a0.w += f.w*w0;
        a1.x += f.x*w1; a1.y += f.y*w1; a1.z += f.z*w1; a1.w += f.w*w1;
        a2.x += f.x*w2; a2.y += f.y*w2; a2.z += f.z*w2; a2.w += f.w*w2;
    }
    const float4* p4 = (const float4*)predl;
    const size_t ob = (size_t)b * PC_ * HW4_ + hw4;
    float4 pl0, pl1, pl2;
    if (wv == 0) { pl0 = p4[ob]; pl1 = p4[ob + 4096]; pl2 = p4[ob + 8192]; }
    else { red[wv-1][0][lane] = a0; red[wv-1][1][lane] = a1; red[wv-1][2][lane] = a2; }
    __syncthreads();
    if (wv == 0) {
#pragma unroll
        for (int w = 0; w < 3; ++w) {
            const float4 x0 = red[w][0][lane], x1 = red[w][1][lane], x2 = red[w][2][lane];
            a0.x += x0.x; a0.y += x0.y; a0.z += x0.z; a0.w += x0.w;
            a1.x += x1.x; a1.y += x1.y; a1.z += x1.z; a1.w += x1.w;
            a2.x += x2.x; a2.y += x2.y; a2.z += x2.z; a2.w += x2.w;
        }
        a0.x += pl0.x; a0.y += pl0.y; a0.z += pl0.z; a0.w += pl0.w;
        a1.x += pl1.x; a1.y += pl1.y; a1.z += pl1.z; a1.w += pl1.w;
        a2.x += pl2.x; a2.y += pl2.y; a2.z += pl2.z; a2.w += pl2.w;
        float4* o4 = (float4*)dout;
        o4[ob]        = a0;
        o4[ob + 4096] = a1;
        o4[ob + 8192] = a2;
    }
}

extern "C" void kernel_launch(void* const* d_in, const int* in_sizes, int n_in,
                              void* d_out, int out_size, void* d_ws, size_t ws_size,
                              hipStream_t stream) {
    const float* feat   = (const float*)d_in[0];
    const float* target = (const float*)d_in[1];
    const float* predl  = (const float*)d_in[2];
    const float* weight = (const float*)d_in[3];
    float* out = (float*)d_out;
    float* wsf = (float*)d_ws;
    (void)ws_size;

    hipLaunchKernelGGL(k1_stats, dim3(B_ * NCHK_), dim3(256), 0, stream,
                       feat, target, predl, wsf);
    hipLaunchKernelGGL(k2a_reduce, dim3(B_ * 11), dim3(256), 0, stream, wsf);
    hipLaunchKernelGGL(k2b_dist, dim3(B_), dim3(256), 0, stream,
                       weight, wsf, out);
    hipLaunchKernelGGL(k4_pred, dim3(B_ * 64), dim3(256), 0, stream,
                       feat, predl, weight, wsf, out);
}